// Round 1
// baseline (285.100 us; speedup 1.0000x reference)
//
#include <hip/hip_runtime.h>
#include <hip/hip_bf16.h>
#include <stdint.h>

typedef __attribute__((ext_vector_type(8))) short bf16x8;
typedef __attribute__((ext_vector_type(4))) float f32x4;

__device__ __forceinline__ unsigned short f2bf(float f) {
  __hip_bfloat16 h = __float2bfloat16(f);
  return *reinterpret_cast<unsigned short*>(&h);
}

// ---------------- absmax over |w| (positive-float bits compare as uints) ----------------
__global__ void absmax_kernel(const float* __restrict__ w, int n4,
                              unsigned int* __restrict__ out) {
  __shared__ unsigned int red[256];
  unsigned int m = 0u;
  const uint4* w4 = reinterpret_cast<const uint4*>(w);
  for (int i = blockIdx.x * blockDim.x + threadIdx.x; i < n4;
       i += gridDim.x * blockDim.x) {
    uint4 v = w4[i];
    m = max(m, v.x & 0x7fffffffu);
    m = max(m, v.y & 0x7fffffffu);
    m = max(m, v.z & 0x7fffffffu);
    m = max(m, v.w & 0x7fffffffu);
  }
  red[threadIdx.x] = m;
  __syncthreads();
  for (int s = 128; s > 0; s >>= 1) {
    if ((int)threadIdx.x < s)
      red[threadIdx.x] = max(red[threadIdx.x], red[threadIdx.x + s]);
    __syncthreads();
  }
  if (threadIdx.x == 0) atomicMax(out, red[0]);
}

// ---------------- fake-quant (round-half-even like jnp.round) + cast to bf16 ----------------
__global__ void quant_kernel(const float* __restrict__ w, int n4,
                             const unsigned int* __restrict__ maxbits,
                             const int* __restrict__ bits,
                             unsigned short* __restrict__ out) {
  const float qmax = (float)((1 << (*bits - 1)) - 1);
  const float scale = __uint_as_float(*maxbits) / qmax;
  const float4* w4 = reinterpret_cast<const float4*>(w);
  ushort4* o4 = reinterpret_cast<ushort4*>(out);
  for (int i = blockIdx.x * blockDim.x + threadIdx.x; i < n4;
       i += gridDim.x * blockDim.x) {
    float4 v = w4[i];
    float a = fminf(fmaxf(rintf(v.x / scale), -qmax), qmax) * scale;
    float b = fminf(fmaxf(rintf(v.y / scale), -qmax), qmax) * scale;
    float c = fminf(fmaxf(rintf(v.z / scale), -qmax), qmax) * scale;
    float d = fminf(fmaxf(rintf(v.w / scale), -qmax), qmax) * scale;
    o4[i] = make_ushort4(f2bf(a), f2bf(b), f2bf(c), f2bf(d));
  }
}

// ---------------- f32 -> bf16 cast for activations ----------------
__global__ void cast_kernel(const float* __restrict__ x, int n4,
                            unsigned short* __restrict__ out) {
  const float4* x4 = reinterpret_cast<const float4*>(x);
  ushort4* o4 = reinterpret_cast<ushort4*>(out);
  for (int i = blockIdx.x * blockDim.x + threadIdx.x; i < n4;
       i += gridDim.x * blockDim.x) {
    float4 v = x4[i];
    o4[i] = make_ushort4(f2bf(v.x), f2bf(v.y), f2bf(v.z), f2bf(v.w));
  }
}

// ---------------- bf16 GEMM, C[M,N] = A[M,K] * B[N,K]^T + bias, optional ReLU ----------------
// m97 structure: 128x128 tile, BK=32, 4 waves (2x2 of 64x64), global_load_lds w=16.
template<bool RELU, bool BF16_OUT>
__global__ __launch_bounds__(256)
void gemm_bt(const unsigned short* __restrict__ A,  // [M,K] bf16 bits
             const unsigned short* __restrict__ B,  // [N,K] bf16 bits
             const float* __restrict__ bias,        // [N]
             void* __restrict__ Cout,               // [M,N] bf16 or f32
             int M, int N, int K) {
  constexpr int BK = 32;
  __shared__ __attribute__((aligned(16))) unsigned short As[128 * BK];
  __shared__ __attribute__((aligned(16))) unsigned short Bs[128 * BK];

  const int tid = threadIdx.x;
  const int lane = tid & 63;
  const int wave = tid >> 6;
  const int wr = wave >> 1;   // 0..1 -> 64-row band
  const int wc = wave & 1;    // 0..1 -> 64-col band
  const long brow = (long)blockIdx.y * 128;
  const long bcol = (long)blockIdx.x * 128;

  f32x4 acc[4][4] = {};

  const int srow = lane >> 2;        // staging: row-within-chunk
  const int scol = (lane & 3) * 8;   // staging: k offset (8 bf16 = 16B)
  const int fr = lane & 15;          // fragment row/col index
  const int kq = (lane >> 4) * 8;    // fragment k base

  for (int k0 = 0; k0 < K; k0 += BK) {
#pragma unroll
    for (int it = 0; it < 2; ++it) {
      const int c = it * 4 + wave;           // chunk 0..7, 16 rows each
      const int row = c * 16 + srow;
      const unsigned short* ga = A + (brow + row) * (long)K + k0 + scol;
      const unsigned short* gb = B + (bcol + row) * (long)K + k0 + scol;
      __builtin_amdgcn_global_load_lds(
          (const __attribute__((address_space(1))) void*)ga,
          (__attribute__((address_space(3))) void*)(As + c * 512), 16, 0, 0);
      __builtin_amdgcn_global_load_lds(
          (const __attribute__((address_space(1))) void*)gb,
          (__attribute__((address_space(3))) void*)(Bs + c * 512), 16, 0, 0);
    }
    __syncthreads();

    bf16x8 a[4], b[4];
#pragma unroll
    for (int m = 0; m < 4; ++m)
      a[m] = *reinterpret_cast<const bf16x8*>(As + (wr * 64 + m * 16 + fr) * BK + kq);
#pragma unroll
    for (int n = 0; n < 4; ++n)
      b[n] = *reinterpret_cast<const bf16x8*>(Bs + (wc * 64 + n * 16 + fr) * BK + kq);
#pragma unroll
    for (int m = 0; m < 4; ++m)
#pragma unroll
      for (int n = 0; n < 4; ++n)
        acc[m][n] = __builtin_amdgcn_mfma_f32_16x16x32_bf16(a[m], b[n], acc[m][n], 0, 0, 0);
    __syncthreads();
  }

  // epilogue: C/D layout col=lane&15, row=(lane>>4)*4+r  [m89/m91 verified]
  const int fq = lane >> 4;
#pragma unroll
  for (int n = 0; n < 4; ++n) {
    const long col = bcol + wc * 64 + n * 16 + fr;
    const float bv = bias[col];
#pragma unroll
    for (int m = 0; m < 4; ++m) {
#pragma unroll
      for (int r = 0; r < 4; ++r) {
        const long row = brow + wr * 64 + m * 16 + fq * 4 + r;
        float v = acc[m][n][r] + bv;
        if (RELU) v = fmaxf(v, 0.0f);
        if (BF16_OUT)
          ((unsigned short*)Cout)[row * N + col] = f2bf(v);
        else
          ((float*)Cout)[row * N + col] = v;
      }
    }
  }
}

extern "C" void kernel_launch(void* const* d_in, const int* in_sizes, int n_in,
                              void* d_out, int out_size, void* d_ws, size_t ws_size,
                              hipStream_t stream) {
  const float* x  = (const float*)d_in[0];
  const float* w1 = (const float*)d_in[1];
  const float* b1 = (const float*)d_in[2];
  const float* w2 = (const float*)d_in[3];
  const float* b2 = (const float*)d_in[4];
  const int* bits = (const int*)d_in[5];

  const int M = 64 * 196;  // 12544 tokens
  const int D = 768, H = 3072;
  const int nx = M * D;        // 9,633,792
  const int nw1 = H * D;       // 2,359,296
  const int nw2 = D * H;       // 2,359,296

  char* ws = (char*)d_ws;
  unsigned int* scales = (unsigned int*)ws;  // [0]=max|w1| bits, [1]=max|w2| bits
  unsigned short* xb  = (unsigned short*)(ws + 256);
  unsigned short* w1q = (unsigned short*)(ws + 256 + (size_t)nx * 2);
  unsigned short* w2q = (unsigned short*)(ws + 256 + (size_t)nx * 2 + (size_t)nw1 * 2);
  unsigned short* hb  = (unsigned short*)(ws + 256 + (size_t)nx * 2 + (size_t)(nw1 + nw2) * 2);

  hipMemsetAsync(scales, 0, 8, stream);
  absmax_kernel<<<832, 256, 0, stream>>>(w1, nw1 / 4, scales + 0);
  absmax_kernel<<<832, 256, 0, stream>>>(w2, nw2 / 4, scales + 1);
  quant_kernel<<<832, 256, 0, stream>>>(w1, nw1 / 4, scales + 0, bits, w1q);
  quant_kernel<<<832, 256, 0, stream>>>(w2, nw2 / 4, scales + 1, bits, w2q);
  cast_kernel<<<2048, 256, 0, stream>>>(x, nx / 4, xb);

  // GEMM1: h = relu(x @ w1^T + b1), [12544,3072] bf16
  gemm_bt<true, true><<<dim3(H / 128, M / 128), 256, 0, stream>>>(xb, w1q, b1, hb, M, H, D);
  // GEMM2: out = h @ w2^T + b2, [12544,768] f32
  gemm_bt<false, false><<<dim3(D / 128, M / 128), 256, 0, stream>>>(hb, w2q, b2, d_out, M, D, H);
}

// Round 2
// 249.882 us; speedup vs baseline: 1.1409x; 1.1409x over previous
//
#include <hip/hip_runtime.h>
#include <hip/hip_bf16.h>
#include <stdint.h>

typedef __attribute__((ext_vector_type(8))) short bf16x8;
typedef __attribute__((ext_vector_type(4))) float f32x4;

__device__ __forceinline__ unsigned short f2bf(float f) {
  __hip_bfloat16 h = __float2bfloat16(f);
  return *reinterpret_cast<unsigned short*>(&h);
}

// ---------------- absmax over |w| (positive-float bits compare as uints) ----------------
__global__ void absmax_kernel(const float* __restrict__ w, int n4,
                              unsigned int* __restrict__ out) {
  __shared__ unsigned int red[256];
  unsigned int m = 0u;
  const uint4* w4 = reinterpret_cast<const uint4*>(w);
  for (int i = blockIdx.x * blockDim.x + threadIdx.x; i < n4;
       i += gridDim.x * blockDim.x) {
    uint4 v = w4[i];
    m = max(m, v.x & 0x7fffffffu);
    m = max(m, v.y & 0x7fffffffu);
    m = max(m, v.z & 0x7fffffffu);
    m = max(m, v.w & 0x7fffffffu);
  }
  red[threadIdx.x] = m;
  __syncthreads();
  for (int s = 128; s > 0; s >>= 1) {
    if ((int)threadIdx.x < s)
      red[threadIdx.x] = max(red[threadIdx.x], red[threadIdx.x + s]);
    __syncthreads();
  }
  if (threadIdx.x == 0) atomicMax(out, red[0]);
}

// ---------------- fake-quant (round-half-even like jnp.round) + cast to bf16 ----------------
__global__ void quant_kernel(const float* __restrict__ w, int n4,
                             const unsigned int* __restrict__ maxbits,
                             const int* __restrict__ bits,
                             unsigned short* __restrict__ out) {
  const float qmax = (float)((1 << (*bits - 1)) - 1);
  const float scale = __uint_as_float(*maxbits) / qmax;
  const float4* w4 = reinterpret_cast<const float4*>(w);
  ushort4* o4 = reinterpret_cast<ushort4*>(out);
  for (int i = blockIdx.x * blockDim.x + threadIdx.x; i < n4;
       i += gridDim.x * blockDim.x) {
    float4 v = w4[i];
    float a = fminf(fmaxf(rintf(v.x / scale), -qmax), qmax) * scale;
    float b = fminf(fmaxf(rintf(v.y / scale), -qmax), qmax) * scale;
    float c = fminf(fmaxf(rintf(v.z / scale), -qmax), qmax) * scale;
    float d = fminf(fmaxf(rintf(v.w / scale), -qmax), qmax) * scale;
    o4[i] = make_ushort4(f2bf(a), f2bf(b), f2bf(c), f2bf(d));
  }
}

// ---------------- f32 -> bf16 cast for activations ----------------
__global__ void cast_kernel(const float* __restrict__ x, int n4,
                            unsigned short* __restrict__ out) {
  const float4* x4 = reinterpret_cast<const float4*>(x);
  ushort4* o4 = reinterpret_cast<ushort4*>(out);
  for (int i = blockIdx.x * blockDim.x + threadIdx.x; i < n4;
       i += gridDim.x * blockDim.x) {
    float4 v = x4[i];
    o4[i] = make_ushort4(f2bf(v.x), f2bf(v.y), f2bf(v.z), f2bf(v.w));
  }
}

// ---------------- bf16 GEMM, C[M,N] = A[M,K] * B[N,K]^T + bias, optional ReLU ----------------
// m97 structure: BMx128 tile, BK=32, 4 waves (2x2), global_load_lds w=16.
// XCD-chunked bijective swizzle (T1/m204): consecutive linear blocks (which
// share an A row-panel across column tiles) land in the same XCD's L2.
template<int BM, bool RELU, bool BF16_OUT>
__global__ __launch_bounds__(256)
void gemm_bt(const unsigned short* __restrict__ A,  // [M,K] bf16 bits
             const unsigned short* __restrict__ B,  // [N,K] bf16 bits
             const float* __restrict__ bias,        // [N]
             void* __restrict__ Cout,               // [M,N] bf16 or f32
             int M, int N, int K, int gx) {
  constexpr int BK = 32;
  constexpr int MF = BM / 32;    // A-frags per wave (BM=128 -> 4, BM=64 -> 2)
  constexpr int NCH = BM / 16;   // A staging chunks of 16 rows
  __shared__ __attribute__((aligned(16))) unsigned short As[BM * BK];
  __shared__ __attribute__((aligned(16))) unsigned short Bs[128 * BK];

  // bijective XCD swizzle (m204): xcd chunk sizes q+1 (first r) / q
  const int nwg = gridDim.x;
  const int orig = blockIdx.x;
  const int q = nwg >> 3, r = nwg & 7;
  const int xcd = orig & 7, cidx = orig >> 3;
  const int wgid = (xcd < r ? xcd * (q + 1) : r * (q + 1) + (xcd - r) * q) + cidx;
  const int bx = wgid % gx;
  const int by = wgid / gx;

  const int tid = threadIdx.x;
  const int lane = tid & 63;
  const int wave = tid >> 6;
  const int wr = wave >> 1;   // wave row band
  const int wc = wave & 1;    // wave col band
  const long brow = (long)by * BM;
  const long bcol = (long)bx * 128;

  f32x4 acc[MF][4] = {};

  const int srow = lane >> 2;        // staging: row-within-chunk
  const int scol = (lane & 3) * 8;   // staging: k offset (8 bf16 = 16B)
  const int fr = lane & 15;          // fragment row/col index
  const int kq = (lane >> 4) * 8;    // fragment k base

  for (int k0 = 0; k0 < K; k0 += BK) {
    // A tile: NCH chunks of 16 rows, 4 chunks per iteration (one per wave)
#pragma unroll
    for (int it = 0; it < NCH / 4; ++it) {
      const int c = it * 4 + wave;
      const unsigned short* ga = A + (brow + c * 16 + srow) * (long)K + k0 + scol;
      __builtin_amdgcn_global_load_lds(
          (const __attribute__((address_space(1))) void*)ga,
          (__attribute__((address_space(3))) void*)(As + c * 512), 16, 0, 0);
    }
    // B tile: always 128 rows = 8 chunks
#pragma unroll
    for (int it = 0; it < 2; ++it) {
      const int c = it * 4 + wave;
      const unsigned short* gb = B + (bcol + c * 16 + srow) * (long)K + k0 + scol;
      __builtin_amdgcn_global_load_lds(
          (const __attribute__((address_space(1))) void*)gb,
          (__attribute__((address_space(3))) void*)(Bs + c * 512), 16, 0, 0);
    }
    __syncthreads();

    bf16x8 a[MF], b[4];
#pragma unroll
    for (int m = 0; m < MF; ++m)
      a[m] = *reinterpret_cast<const bf16x8*>(As + (wr * (MF * 16) + m * 16 + fr) * BK + kq);
#pragma unroll
    for (int n = 0; n < 4; ++n)
      b[n] = *reinterpret_cast<const bf16x8*>(Bs + (wc * 64 + n * 16 + fr) * BK + kq);
#pragma unroll
    for (int m = 0; m < MF; ++m)
#pragma unroll
      for (int n = 0; n < 4; ++n)
        acc[m][n] = __builtin_amdgcn_mfma_f32_16x16x32_bf16(a[m], b[n], acc[m][n], 0, 0, 0);
    __syncthreads();
  }

  // epilogue: C/D layout col=lane&15, row=(lane>>4)*4+r  [m89/m91 verified]
  const int fq = lane >> 4;
#pragma unroll
  for (int n = 0; n < 4; ++n) {
    const long col = bcol + wc * 64 + n * 16 + fr;
    const float bv = bias[col];
#pragma unroll
    for (int m = 0; m < MF; ++m) {
#pragma unroll
      for (int rr = 0; rr < 4; ++rr) {
        const long row = brow + wr * (MF * 16) + m * 16 + fq * 4 + rr;
        float v = acc[m][n][rr] + bv;
        if (RELU) v = fmaxf(v, 0.0f);
        if (BF16_OUT)
          ((unsigned short*)Cout)[row * N + col] = f2bf(v);
        else
          ((float*)Cout)[row * N + col] = v;
      }
    }
  }
}

extern "C" void kernel_launch(void* const* d_in, const int* in_sizes, int n_in,
                              void* d_out, int out_size, void* d_ws, size_t ws_size,
                              hipStream_t stream) {
  const float* x  = (const float*)d_in[0];
  const float* w1 = (const float*)d_in[1];
  const float* b1 = (const float*)d_in[2];
  const float* w2 = (const float*)d_in[3];
  const float* b2 = (const float*)d_in[4];
  const int* bits = (const int*)d_in[5];

  const int M = 64 * 196;  // 12544 tokens
  const int D = 768, H = 3072;
  const int nx = M * D;
  const int nw1 = H * D;
  const int nw2 = D * H;

  char* ws = (char*)d_ws;
  unsigned int* scales = (unsigned int*)ws;
  unsigned short* xb  = (unsigned short*)(ws + 256);
  unsigned short* w1q = (unsigned short*)(ws + 256 + (size_t)nx * 2);
  unsigned short* w2q = (unsigned short*)(ws + 256 + (size_t)nx * 2 + (size_t)nw1 * 2);
  unsigned short* hb  = (unsigned short*)(ws + 256 + (size_t)nx * 2 + (size_t)(nw1 + nw2) * 2);

  hipMemsetAsync(scales, 0, 8, stream);
  absmax_kernel<<<832, 256, 0, stream>>>(w1, nw1 / 4, scales + 0);
  absmax_kernel<<<832, 256, 0, stream>>>(w2, nw2 / 4, scales + 1);
  quant_kernel<<<832, 256, 0, stream>>>(w1, nw1 / 4, scales + 0, bits, w1q);
  quant_kernel<<<832, 256, 0, stream>>>(w2, nw2 / 4, scales + 1, bits, w2q);
  cast_kernel<<<2048, 256, 0, stream>>>(x, nx / 4, xb);

  // GEMM1: h = relu(x @ w1^T + b1), [12544,3072] bf16 ; 24x98 = 2352 blocks
  gemm_bt<128, true, true><<<(H / 128) * (M / 128), 256, 0, stream>>>(
      xb, w1q, b1, hb, M, H, D, H / 128);
  // GEMM2: out = h @ w2^T + b2, [12544,768] f32 ; BM=64 -> 6x196 = 1176 blocks
  gemm_bt<64, false, false><<<(D / 128) * (M / 64), 256, 0, stream>>>(
      hb, w2q, b2, d_out, M, D, H, D / 128);
}

// Round 3
// 212.103 us; speedup vs baseline: 1.3442x; 1.1781x over previous
//
#include <hip/hip_runtime.h>
#include <hip/hip_bf16.h>
#include <stdint.h>

typedef __attribute__((ext_vector_type(8))) short bf16x8;
typedef __attribute__((ext_vector_type(4))) float f32x4;

__device__ __forceinline__ unsigned short f2bf(float f) {
  __hip_bfloat16 h = __float2bfloat16(f);
  return *reinterpret_cast<unsigned short*>(&h);
}

// ---------------- absmax over |w| (positive-float bits compare as uints) ----------------
__global__ void absmax_kernel(const float* __restrict__ w, int n4,
                              unsigned int* __restrict__ out) {
  __shared__ unsigned int red[256];
  unsigned int m = 0u;
  const uint4* w4 = reinterpret_cast<const uint4*>(w);
  for (int i = blockIdx.x * blockDim.x + threadIdx.x; i < n4;
       i += gridDim.x * blockDim.x) {
    uint4 v = w4[i];
    m = max(m, v.x & 0x7fffffffu);
    m = max(m, v.y & 0x7fffffffu);
    m = max(m, v.z & 0x7fffffffu);
    m = max(m, v.w & 0x7fffffffu);
  }
  red[threadIdx.x] = m;
  __syncthreads();
  for (int s = 128; s > 0; s >>= 1) {
    if ((int)threadIdx.x < s)
      red[threadIdx.x] = max(red[threadIdx.x], red[threadIdx.x + s]);
    __syncthreads();
  }
  if (threadIdx.x == 0) atomicMax(out, red[0]);
}

// ---------------- fake-quant (round-half-even like jnp.round) + cast to bf16 ----------------
__global__ void quant_kernel(const float* __restrict__ w, int n4,
                             const unsigned int* __restrict__ maxbits,
                             const int* __restrict__ bits,
                             unsigned short* __restrict__ out) {
  const float qmax = (float)((1 << (*bits - 1)) - 1);
  const float scale = __uint_as_float(*maxbits) / qmax;
  const float4* w4 = reinterpret_cast<const float4*>(w);
  ushort4* o4 = reinterpret_cast<ushort4*>(out);
  for (int i = blockIdx.x * blockDim.x + threadIdx.x; i < n4;
       i += gridDim.x * blockDim.x) {
    float4 v = w4[i];
    float a = fminf(fmaxf(rintf(v.x / scale), -qmax), qmax) * scale;
    float b = fminf(fmaxf(rintf(v.y / scale), -qmax), qmax) * scale;
    float c = fminf(fmaxf(rintf(v.z / scale), -qmax), qmax) * scale;
    float d = fminf(fmaxf(rintf(v.w / scale), -qmax), qmax) * scale;
    o4[i] = make_ushort4(f2bf(a), f2bf(b), f2bf(c), f2bf(d));
  }
}

// ---------------- f32 -> bf16 cast for activations ----------------
__global__ void cast_kernel(const float* __restrict__ x, int n4,
                            unsigned short* __restrict__ out) {
  const float4* x4 = reinterpret_cast<const float4*>(x);
  ushort4* o4 = reinterpret_cast<ushort4*>(out);
  for (int i = blockIdx.x * blockDim.x + threadIdx.x; i < n4;
       i += gridDim.x * blockDim.x) {
    float4 v = x4[i];
    o4[i] = make_ushort4(f2bf(v.x), f2bf(v.y), f2bf(v.z), f2bf(v.w));
  }
}

// ---------------- bf16 GEMM, C[M,N] = A[M,K] * B[N,K]^T + bias, optional ReLU ----------------
// m97 2-barrier structure, BK=64, 4 waves (2x2), global_load_lds w=16.
// Bank-conflict fix (T2 via rule 21): LDS stays linear [rows][64]; the GLOBAL
// source address is pre-swizzled per-lane (slot ^= row&7 within each row's
// eight 16B slots), and ds_read applies the same XOR. global_load_lds writes
// 8 rows x 8 slots = 1024B contiguous per instruction.
template<int BM, bool RELU, bool BF16_OUT>
__global__ __launch_bounds__(256)
void gemm_bt(const unsigned short* __restrict__ A,  // [M,K] bf16 bits
             const unsigned short* __restrict__ B,  // [N,K] bf16 bits
             const float* __restrict__ bias,        // [N]
             void* __restrict__ Cout,               // [M,N] bf16 or f32
             int M, int N, int K, int gx) {
  constexpr int BK = 64;
  constexpr int MF = BM / 32;    // A-frags per wave (BM=128 -> 4, BM=64 -> 2)
  __shared__ __attribute__((aligned(16))) unsigned short As[BM * BK];
  __shared__ __attribute__((aligned(16))) unsigned short Bs[128 * BK];

  // bijective XCD swizzle (T1/m204)
  const int nwg = gridDim.x;
  const int orig = blockIdx.x;
  const int q = nwg >> 3, r = nwg & 7;
  const int xcd = orig & 7, cidx = orig >> 3;
  const int wgid = (xcd < r ? xcd * (q + 1) : r * (q + 1) + (xcd - r) * q) + cidx;
  const int bx = wgid % gx;
  const int by = wgid / gx;

  const int tid = threadIdx.x;
  const int lane = tid & 63;
  const int wave = tid >> 6;
  const int wr = wave >> 1;
  const int wc = wave & 1;
  const long brow = (long)by * BM;
  const long bcol = (long)bx * 128;

  f32x4 acc[MF][4] = {};

  // staging: chunk = 8 rows x 64 elems (1KB). lane -> row l>>3, slot l&7,
  // global slot pre-swizzled: (l&7) ^ (l>>3)
  const int srow = lane >> 3;
  const int gslot = ((lane & 7) ^ (lane >> 3)) * 8;  // element offset in row
  const int fr = lane & 15;                          // fragment row index
  const int fs = lane >> 4;                          // fragment k-slot (16B) base

  for (int k0 = 0; k0 < K; k0 += BK) {
    // A tile: BM/8 chunks, 4 per staging iteration
#pragma unroll
    for (int it = 0; it < BM / 32; ++it) {
      const int c = it * 4 + wave;
      const unsigned short* ga = A + (brow + c * 8 + srow) * (long)K + k0 + gslot;
      __builtin_amdgcn_global_load_lds(
          (const __attribute__((address_space(1))) void*)ga,
          (__attribute__((address_space(3))) void*)(As + c * 512), 16, 0, 0);
    }
    // B tile: 128/8 = 16 chunks
#pragma unroll
    for (int it = 0; it < 4; ++it) {
      const int c = it * 4 + wave;
      const unsigned short* gb = B + (bcol + c * 8 + srow) * (long)K + k0 + gslot;
      __builtin_amdgcn_global_load_lds(
          (const __attribute__((address_space(1))) void*)gb,
          (__attribute__((address_space(3))) void*)(Bs + c * 512), 16, 0, 0);
    }
    __syncthreads();

    // two K=32 sub-steps within the staged 64
#pragma unroll
    for (int kk = 0; kk < 2; ++kk) {
      const int s = kk * 4 + fs;  // logical 16B slot within row
      bf16x8 a[MF], b[4];
#pragma unroll
      for (int m = 0; m < MF; ++m) {
        const int row = wr * (MF * 16) + m * 16 + fr;
        a[m] = *reinterpret_cast<const bf16x8*>(As + row * BK + ((s ^ (row & 7)) * 8));
      }
#pragma unroll
      for (int n = 0; n < 4; ++n) {
        const int row = wc * 64 + n * 16 + fr;
        b[n] = *reinterpret_cast<const bf16x8*>(Bs + row * BK + ((s ^ (row & 7)) * 8));
      }
#pragma unroll
      for (int m = 0; m < MF; ++m)
#pragma unroll
        for (int n = 0; n < 4; ++n)
          acc[m][n] = __builtin_amdgcn_mfma_f32_16x16x32_bf16(a[m], b[n], acc[m][n], 0, 0, 0);
    }
    __syncthreads();
  }

  // epilogue: C/D layout col=lane&15, row=(lane>>4)*4+r  [m89/m91 verified]
  const int fq = lane >> 4;
#pragma unroll
  for (int n = 0; n < 4; ++n) {
    const long col = bcol + wc * 64 + n * 16 + fr;
    const float bv = bias[col];
#pragma unroll
    for (int m = 0; m < MF; ++m) {
#pragma unroll
      for (int rr = 0; rr < 4; ++rr) {
        const long row = brow + wr * (MF * 16) + m * 16 + fq * 4 + rr;
        float v = acc[m][n][rr] + bv;
        if (RELU) v = fmaxf(v, 0.0f);
        if (BF16_OUT)
          ((unsigned short*)Cout)[row * N + col] = f2bf(v);
        else
          ((float*)Cout)[row * N + col] = v;
      }
    }
  }
}

extern "C" void kernel_launch(void* const* d_in, const int* in_sizes, int n_in,
                              void* d_out, int out_size, void* d_ws, size_t ws_size,
                              hipStream_t stream) {
  const float* x  = (const float*)d_in[0];
  const float* w1 = (const float*)d_in[1];
  const float* b1 = (const float*)d_in[2];
  const float* w2 = (const float*)d_in[3];
  const float* b2 = (const float*)d_in[4];
  const int* bits = (const int*)d_in[5];

  const int M = 64 * 196;  // 12544 tokens
  const int D = 768, H = 3072;
  const int nx = M * D;
  const int nw1 = H * D;
  const int nw2 = D * H;

  char* ws = (char*)d_ws;
  unsigned int* scales = (unsigned int*)ws;
  unsigned short* xb  = (unsigned short*)(ws + 256);
  unsigned short* w1q = (unsigned short*)(ws + 256 + (size_t)nx * 2);
  unsigned short* w2q = (unsigned short*)(ws + 256 + (size_t)nx * 2 + (size_t)nw1 * 2);
  unsigned short* hb  = (unsigned short*)(ws + 256 + (size_t)nx * 2 + (size_t)(nw1 + nw2) * 2);

  hipMemsetAsync(scales, 0, 8, stream);
  absmax_kernel<<<832, 256, 0, stream>>>(w1, nw1 / 4, scales + 0);
  absmax_kernel<<<832, 256, 0, stream>>>(w2, nw2 / 4, scales + 1);
  quant_kernel<<<832, 256, 0, stream>>>(w1, nw1 / 4, scales + 0, bits, w1q);
  quant_kernel<<<832, 256, 0, stream>>>(w2, nw2 / 4, scales + 1, bits, w2q);
  cast_kernel<<<2048, 256, 0, stream>>>(x, nx / 4, xb);

  // GEMM1: h = relu(x @ w1^T + b1), [12544,3072] bf16 ; 24x98 = 2352 blocks
  gemm_bt<128, true, true><<<(H / 128) * (M / 128), 256, 0, stream>>>(
      xb, w1q, b1, hb, M, H, D, H / 128);
  // GEMM2: out = h @ w2^T + b2, [12544,768] f32 ; BM=64 -> 6x196 = 1176 blocks
  gemm_bt<64, false, false><<<(D / 128) * (M / 64), 256, 0, stream>>>(
      hb, w2q, b2, d_out, M, D, H, D / 128);
}

// Round 4
// 197.287 us; speedup vs baseline: 1.4451x; 1.0751x over previous
//
#include <hip/hip_runtime.h>
#include <hip/hip_bf16.h>
#include <stdint.h>

typedef __attribute__((ext_vector_type(8))) short bf16x8;
typedef __attribute__((ext_vector_type(4))) float f32x4;

__device__ __forceinline__ unsigned short f2bf(float f) {
  __hip_bfloat16 h = __float2bfloat16(f);
  return *reinterpret_cast<unsigned short*>(&h);
}

// ---------------- absmax over both weights (gridDim.y = tensor id) ----------------
__global__ void absmax2_kernel(const float* __restrict__ w1, const float* __restrict__ w2,
                               int n4, unsigned int* __restrict__ out) {
  const float* w = blockIdx.y ? w2 : w1;
  __shared__ unsigned int red[256];
  unsigned int m = 0u;
  const uint4* w4 = reinterpret_cast<const uint4*>(w);
  for (int i = blockIdx.x * blockDim.x + threadIdx.x; i < n4;
       i += gridDim.x * blockDim.x) {
    uint4 v = w4[i];
    m = max(m, v.x & 0x7fffffffu);
    m = max(m, v.y & 0x7fffffffu);
    m = max(m, v.z & 0x7fffffffu);
    m = max(m, v.w & 0x7fffffffu);
  }
  red[threadIdx.x] = m;
  __syncthreads();
  for (int s = 128; s > 0; s >>= 1) {
    if ((int)threadIdx.x < s)
      red[threadIdx.x] = max(red[threadIdx.x], red[threadIdx.x + s]);
    __syncthreads();
  }
  if (threadIdx.x == 0) atomicMax(out + blockIdx.y, red[0]);
}

// ---------------- fake-quant both weights (round-half-even) + cast to bf16 ----------------
__global__ void quant2_kernel(const float* __restrict__ w1, const float* __restrict__ w2,
                              int n4, const unsigned int* __restrict__ maxbits,
                              const int* __restrict__ bits,
                              unsigned short* __restrict__ o1, unsigned short* __restrict__ o2) {
  const float* w = blockIdx.y ? w2 : w1;
  unsigned short* o = blockIdx.y ? o2 : o1;
  const float qmax = (float)((1 << (*bits - 1)) - 1);
  const float scale = __uint_as_float(maxbits[blockIdx.y]) / qmax;
  const float4* w4 = reinterpret_cast<const float4*>(w);
  ushort4* o4 = reinterpret_cast<ushort4*>(o);
  for (int i = blockIdx.x * blockDim.x + threadIdx.x; i < n4;
       i += gridDim.x * blockDim.x) {
    float4 v = w4[i];
    float a = fminf(fmaxf(rintf(v.x / scale), -qmax), qmax) * scale;
    float b = fminf(fmaxf(rintf(v.y / scale), -qmax), qmax) * scale;
    float c = fminf(fmaxf(rintf(v.z / scale), -qmax), qmax) * scale;
    float d = fminf(fmaxf(rintf(v.w / scale), -qmax), qmax) * scale;
    o4[i] = make_ushort4(f2bf(a), f2bf(b), f2bf(c), f2bf(d));
  }
}

// ---------------- f32 -> bf16 cast for activations ----------------
__global__ void cast_kernel(const float* __restrict__ x, int n4,
                            unsigned short* __restrict__ out) {
  const float4* x4 = reinterpret_cast<const float4*>(x);
  ushort4* o4 = reinterpret_cast<ushort4*>(out);
  for (int i = blockIdx.x * blockDim.x + threadIdx.x; i < n4;
       i += gridDim.x * blockDim.x) {
    float4 v = x4[i];
    o4[i] = make_ushort4(f2bf(v.x), f2bf(v.y), f2bf(v.z), f2bf(v.w));
  }
}

// ---------------- bf16 GEMM, C[M,N] = A[M,K] * B[N,K]^T + bias, optional ReLU ----------------
// T3+T4: double-buffered LDS, 2-deep prefetch, COUNTED vmcnt (never 0 in the
// main loop). Per-iteration: [wait vmcnt(L); barrier] -> ds_read+MFMA ->
// [lgkmcnt(0); barrier] -> stage(t+2 -> just-freed buffer).
// T2 via rule 21: linear LDS, global source pre-swizzled (slot ^= row&7),
// same XOR on ds_read -> 0 bank conflicts (verified round 3).
template<int BM, bool RELU, bool BF16_OUT>
__global__ __launch_bounds__(256)
void gemm_bt(const unsigned short* __restrict__ A,  // [M,K] bf16 bits
             const unsigned short* __restrict__ B,  // [N,K] bf16 bits
             const float* __restrict__ bias,        // [N]
             void* __restrict__ Cout,               // [M,N] bf16 or f32
             int M, int N, int K, int gx) {
  constexpr int BK = 64;
  constexpr int MF = BM / 32;    // A-frags per wave
  __shared__ __attribute__((aligned(16))) unsigned short As[2][BM * BK];
  __shared__ __attribute__((aligned(16))) unsigned short Bs[2][128 * BK];

  // bijective XCD swizzle (T1/m204)
  const int nwg = gridDim.x;
  const int orig = blockIdx.x;
  const int q = nwg >> 3, r = nwg & 7;
  const int xcd = orig & 7, cidx = orig >> 3;
  const int wgid = (xcd < r ? xcd * (q + 1) : r * (q + 1) + (xcd - r) * q) + cidx;
  const int bx = wgid % gx;
  const int by = wgid / gx;

  const int tid = threadIdx.x;
  const int lane = tid & 63;
  const int wave = tid >> 6;
  const int wr = wave >> 1;
  const int wc = wave & 1;
  const long brow = (long)by * BM;
  const long bcol = (long)bx * 128;

  f32x4 acc[MF][4] = {};

  // staging: chunk = 8 rows x 64 elems (1KB); global slot pre-swizzled
  const int srow = lane >> 3;
  const int gslot = ((lane & 7) ^ (lane >> 3)) * 8;
  const int fr = lane & 15;
  const int fs = lane >> 4;

  auto stage = [&](int k0, int b) {
#pragma unroll
    for (int it = 0; it < BM / 32; ++it) {
      const int c = it * 4 + wave;
      const unsigned short* ga = A + (brow + c * 8 + srow) * (long)K + k0 + gslot;
      __builtin_amdgcn_global_load_lds(
          (const __attribute__((address_space(1))) void*)ga,
          (__attribute__((address_space(3))) void*)(&As[b][c * 512]), 16, 0, 0);
    }
#pragma unroll
    for (int it = 0; it < 4; ++it) {
      const int c = it * 4 + wave;
      const unsigned short* gb = B + (bcol + c * 8 + srow) * (long)K + k0 + gslot;
      __builtin_amdgcn_global_load_lds(
          (const __attribute__((address_space(1))) void*)gb,
          (__attribute__((address_space(3))) void*)(&Bs[b][c * 512]), 16, 0, 0);
    }
  };

  const int nt = K / BK;
  stage(0, 0);
  stage(BK, 1);

  for (int t = 0; t < nt; ++t) {
    const int b = t & 1;
    // wait for stage(t); stage(t+1)'s loads (8 or 6) may remain in flight
    if (t < nt - 1) {
      if constexpr (BM == 128) asm volatile("s_waitcnt vmcnt(8)" ::: "memory");
      else                     asm volatile("s_waitcnt vmcnt(6)" ::: "memory");
    } else {
      asm volatile("s_waitcnt vmcnt(0)" ::: "memory");
    }
    __builtin_amdgcn_s_barrier();

    const unsigned short* as = &As[b][0];
    const unsigned short* bs = &Bs[b][0];
#pragma unroll
    for (int kk = 0; kk < 2; ++kk) {
      const int s = kk * 4 + fs;
      bf16x8 a[MF], bb[4];
#pragma unroll
      for (int m = 0; m < MF; ++m) {
        const int row = wr * (MF * 16) + m * 16 + fr;
        a[m] = *reinterpret_cast<const bf16x8*>(as + row * BK + ((s ^ (row & 7)) * 8));
      }
#pragma unroll
      for (int n = 0; n < 4; ++n) {
        const int row = wc * 64 + n * 16 + fr;
        bb[n] = *reinterpret_cast<const bf16x8*>(bs + row * BK + ((s ^ (row & 7)) * 8));
      }
#pragma unroll
      for (int m = 0; m < MF; ++m)
#pragma unroll
        for (int n = 0; n < 4; ++n)
          acc[m][n] = __builtin_amdgcn_mfma_f32_16x16x32_bf16(a[m], bb[n], acc[m][n], 0, 0, 0);
    }

    asm volatile("s_waitcnt lgkmcnt(0)" ::: "memory");
    __builtin_amdgcn_sched_barrier(0);
    __builtin_amdgcn_s_barrier();
    if (t + 2 < nt) stage((t + 2) * BK, b);
  }

  // epilogue: C/D layout col=lane&15, row=(lane>>4)*4+r  [m89/m91 verified]
  const int fq = lane >> 4;
#pragma unroll
  for (int n = 0; n < 4; ++n) {
    const long col = bcol + wc * 64 + n * 16 + fr;
    const float bv = bias[col];
#pragma unroll
    for (int m = 0; m < MF; ++m) {
#pragma unroll
      for (int rr = 0; rr < 4; ++rr) {
        const long row = brow + wr * (MF * 16) + m * 16 + fq * 4 + rr;
        float v = acc[m][n][rr] + bv;
        if (RELU) v = fmaxf(v, 0.0f);
        if (BF16_OUT)
          ((unsigned short*)Cout)[row * N + col] = f2bf(v);
        else
          ((float*)Cout)[row * N + col] = v;
      }
    }
  }
}

extern "C" void kernel_launch(void* const* d_in, const int* in_sizes, int n_in,
                              void* d_out, int out_size, void* d_ws, size_t ws_size,
                              hipStream_t stream) {
  const float* x  = (const float*)d_in[0];
  const float* w1 = (const float*)d_in[1];
  const float* b1 = (const float*)d_in[2];
  const float* w2 = (const float*)d_in[3];
  const float* b2 = (const float*)d_in[4];
  const int* bits = (const int*)d_in[5];

  const int M = 64 * 196;  // 12544 tokens
  const int D = 768, H = 3072;
  const int nx = M * D;
  const int nw1 = H * D;
  const int nw2 = D * H;

  char* ws = (char*)d_ws;
  unsigned int* scales = (unsigned int*)ws;
  unsigned short* xb  = (unsigned short*)(ws + 256);
  unsigned short* w1q = (unsigned short*)(ws + 256 + (size_t)nx * 2);
  unsigned short* w2q = (unsigned short*)(ws + 256 + (size_t)nx * 2 + (size_t)nw1 * 2);
  unsigned short* hb  = (unsigned short*)(ws + 256 + (size_t)nx * 2 + (size_t)(nw1 + nw2) * 2);

  hipMemsetAsync(scales, 0, 8, stream);
  absmax2_kernel<<<dim3(512, 2), 256, 0, stream>>>(w1, w2, nw1 / 4, scales);
  quant2_kernel<<<dim3(512, 2), 256, 0, stream>>>(w1, w2, nw1 / 4, scales, bits, w1q, w2q);
  cast_kernel<<<2048, 256, 0, stream>>>(x, nx / 4, xb);

  // GEMM1: h = relu(x @ w1^T + b1), [12544,3072] bf16 ; 24x98 = 2352 blocks
  gemm_bt<128, true, true><<<(H / 128) * (M / 128), 256, 0, stream>>>(
      xb, w1q, b1, hb, M, H, D, H / 128);
  // GEMM2: out = h @ w2^T + b2, [12544,768] f32 ; BM=64 -> 6x196 = 1176 blocks
  gemm_bt<64, false, false><<<(D / 128) * (M / 64), 256, 0, stream>>>(
      hb, w2q, b2, d_out, M, D, H, D / 128);
}